// Round 1
// baseline (1721.124 us; speedup 1.0000x reference)
//
#include <hip/hip_runtime.h>
#include <math.h>

#define DIM      1024
#define BM       128
#define BN       128
#define BK       32
#define NSTRIPES 16
#define PAD      4

// ---------------- kernel 1: inverse L2 norms of target rows ----------------
__global__ void inv_norm_kernel(const float* __restrict__ t,
                                float* __restrict__ inv_t, int n) {
    int wave = (int)((blockIdx.x * blockDim.x + threadIdx.x) >> 6);
    int lane = threadIdx.x & 63;
    if (wave >= n) return;
    const float4* row = (const float4*)(t + (size_t)wave * DIM);
    float ss = 0.f;
#pragma unroll
    for (int p = 0; p < 4; ++p) {
        float4 v = row[lane + 64 * p];
        ss = fmaf(v.x, v.x, ss);
        ss = fmaf(v.y, v.y, ss);
        ss = fmaf(v.z, v.z, ss);
        ss = fmaf(v.w, v.w, ss);
    }
#pragma unroll
    for (int off = 32; off; off >>= 1) ss += __shfl_xor(ss, off, 64);
    if (lane == 0) inv_t[wave] = 1.0f / fmaxf(sqrtf(ss), 1e-12f);
}

// ------------- kernel 2: fused f32 GEMM (A.B^T) + running argmax -----------
// grid: (M/BM, NSTRIPES); block: 256 threads (16x16, each 8x8 micro-tile)
__global__ __launch_bounds__(256) void fused_argmax_kernel(
    const float* __restrict__ A,      // source [M][DIM]
    const float* __restrict__ B,      // target [N][DIM]
    const float* __restrict__ inv_t,  // [N]
    float* __restrict__ sbest,        // [NSTRIPES][M]
    int* __restrict__ sidx,           // [NSTRIPES][M]
    int M, int N) {
    __shared__ __align__(16) float sA[BK][BM + PAD];
    __shared__ __align__(16) float sB[BK][BN + PAD];

    const int tid = threadIdx.x;
    const int tx = tid & 15;
    const int ty = tid >> 4;
    const int rowBase = blockIdx.x * BM;
    const int stripe = blockIdx.y;
    const int stripeN = N / NSTRIPES;
    const int colBase0 = stripe * stripeN;

    const int lr = tid >> 3;         // 0..31: row within 32-row pass
    const int lk = (tid & 7) << 2;   // 0,4,...,28: k chunk

    float best[8];
    int bidx[8];
#pragma unroll
    for (int i = 0; i < 8; ++i) { best[i] = -1e30f; bidx[i] = 0; }

    for (int nt = 0; nt < stripeN / BN; ++nt) {
        const int colBase = colBase0 + nt * BN;
        float acc[8][8];
#pragma unroll
        for (int i = 0; i < 8; ++i)
#pragma unroll
            for (int j = 0; j < 8; ++j) acc[i][j] = 0.f;

        for (int kt = 0; kt < DIM / BK; ++kt) {
            const int k0 = kt * BK;
            __syncthreads();  // protect previous iteration's LDS reads
#pragma unroll
            for (int p = 0; p < 4; ++p) {
                int r = lr + 32 * p;
                float4 va = *(const float4*)(A + (size_t)(rowBase + r) * DIM + k0 + lk);
                sA[lk + 0][r] = va.x;
                sA[lk + 1][r] = va.y;
                sA[lk + 2][r] = va.z;
                sA[lk + 3][r] = va.w;
                float4 vb = *(const float4*)(B + (size_t)(colBase + r) * DIM + k0 + lk);
                sB[lk + 0][r] = vb.x;
                sB[lk + 1][r] = vb.y;
                sB[lk + 2][r] = vb.z;
                sB[lk + 3][r] = vb.w;
            }
            __syncthreads();
#pragma unroll 4
            for (int k = 0; k < BK; ++k) {
                float4 af0 = *(const float4*)&sA[k][ty * 8];
                float4 af1 = *(const float4*)&sA[k][ty * 8 + 4];
                float4 bf0 = *(const float4*)&sB[k][tx * 8];
                float4 bf1 = *(const float4*)&sB[k][tx * 8 + 4];
                float a[8] = {af0.x, af0.y, af0.z, af0.w, af1.x, af1.y, af1.z, af1.w};
                float b[8] = {bf0.x, bf0.y, bf0.z, bf0.w, bf1.x, bf1.y, bf1.z, bf1.w};
#pragma unroll
                for (int i = 0; i < 8; ++i)
#pragma unroll
                    for (int j = 0; j < 8; ++j)
                        acc[i][j] = fmaf(a[i], b[j], acc[i][j]);
            }
        }
        // compare this tile's sims against running best (cols ascending)
#pragma unroll
        for (int j = 0; j < 8; ++j) {
            int col = colBase + tx * 8 + j;
            float it = inv_t[col];
#pragma unroll
            for (int i = 0; i < 8; ++i) {
                float s = acc[i][j] * it;
                if (s > best[i]) { best[i] = s; bidx[i] = col; }
            }
        }
    }

    // reduce across the 16 tx lanes sharing the same rows (same wave)
#pragma unroll
    for (int i = 0; i < 8; ++i) {
        float v = best[i];
        int ix = bidx[i];
#pragma unroll
        for (int off = 1; off < 16; off <<= 1) {
            float v2 = __shfl_xor(v, off, 64);
            int ix2 = __shfl_xor(ix, off, 64);
            if (v2 > v || (v2 == v && ix2 < ix)) { v = v2; ix = ix2; }
        }
        if (tx == 0) {
            int row = rowBase + ty * 8 + i;
            sbest[(size_t)stripe * M + row] = v;
            sidx[(size_t)stripe * M + row] = ix;
        }
    }
}

// ------------- kernel 3: reduce stripes + gather winning target row --------
__global__ void gather_kernel(const float* __restrict__ B,
                              const float* __restrict__ sbest,
                              const int* __restrict__ sidx,
                              float* __restrict__ out, int M) {
    int row = blockIdx.x;
    float v = -1e30f;
    int ix = 0;
#pragma unroll
    for (int s = 0; s < NSTRIPES; ++s) {
        float v2 = sbest[(size_t)s * M + row];
        int ix2 = sidx[(size_t)s * M + row];
        if (v2 > v || (v2 == v && ix2 < ix)) { v = v2; ix = ix2; }
    }
    const float4* srcp = (const float4*)(B + (size_t)ix * DIM);
    float4* dstp = (float4*)(out + (size_t)row * DIM);
    dstp[threadIdx.x] = srcp[threadIdx.x];
}

extern "C" void kernel_launch(void* const* d_in, const int* in_sizes, int n_in,
                              void* d_out, int out_size, void* d_ws, size_t ws_size,
                              hipStream_t stream) {
    const float* src = (const float*)d_in[0];
    const float* tgt = (const float*)d_in[1];
    float* out = (float*)d_out;
    int M = in_sizes[0] / DIM;
    int N = in_sizes[1] / DIM;

    char* ws = (char*)d_ws;
    float* sbest = (float*)ws;
    int* sidx = (int*)(ws + (size_t)NSTRIPES * M * sizeof(float));
    float* inv_t = (float*)(ws + (size_t)NSTRIPES * M * (sizeof(float) + sizeof(int)));

    inv_norm_kernel<<<dim3((N + 3) / 4), 256, 0, stream>>>(tgt, inv_t, N);
    fused_argmax_kernel<<<dim3(M / BM, NSTRIPES), 256, 0, stream>>>(
        src, tgt, inv_t, sbest, sidx, M, N);
    gather_kernel<<<dim3(M), 256, 0, stream>>>(tgt, sbest, sidx, out, M);
}

// Round 5
// 538.122 us; speedup vs baseline: 3.1984x; 3.1984x over previous
//
#include <hip/hip_runtime.h>
#include <math.h>

#define DIM      1024
#define NSTRIPES 16     // fallback path only
#define PAD      4
#define GROUPW   16
#define MAXSLOTS 32
// Screen values are dot*inv_t = |src_row| * cos_sim (|src_row| ~ 32), so bf16
// screen noise is sigma ~= 1.6e-3 in SCREEN units. EPS must be ~35 sigma of
// the pairwise error difference (sigma_diff ~= 2.3e-3): 0.08.
#define EPS      0.08f

typedef __attribute__((ext_vector_type(8))) __bf16 bf16x8;
typedef __attribute__((ext_vector_type(4))) float f32x4;
typedef __attribute__((ext_vector_type(4))) unsigned int u32x4;

// ---------------- inverse L2 norms of target rows (both paths) -------------
__global__ void inv_norm_kernel(const float* __restrict__ t,
                                float* __restrict__ inv_t, int n) {
    int wave = (int)((blockIdx.x * blockDim.x + threadIdx.x) >> 6);
    int lane = threadIdx.x & 63;
    if (wave >= n) return;
    const float4* row = (const float4*)(t + (size_t)wave * DIM);
    float ss = 0.f;
#pragma unroll
    for (int p = 0; p < 4; ++p) {
        float4 v = row[lane + 64 * p];
        ss = fmaf(v.x, v.x, ss);
        ss = fmaf(v.y, v.y, ss);
        ss = fmaf(v.z, v.z, ss);
        ss = fmaf(v.w, v.w, ss);
    }
#pragma unroll
    for (int off = 32; off; off >>= 1) ss += __shfl_xor(ss, off, 64);
    if (lane == 0) inv_t[wave] = 1.0f / fmaxf(sqrtf(ss), 1e-12f);
}

// ---------------- f32 -> bf16 conversion (8 elems/thread) ------------------
__global__ void convert_bf16_kernel(const float* __restrict__ in,
                                    unsigned short* __restrict__ outp, int n8) {
    int i = blockIdx.x * blockDim.x + threadIdx.x;
    if (i >= n8) return;
    const float4* p = (const float4*)in;
    float4 v0 = p[2 * i], v1 = p[2 * i + 1];
    bf16x8 o;
    o[0] = (__bf16)v0.x; o[1] = (__bf16)v0.y; o[2] = (__bf16)v0.z; o[3] = (__bf16)v0.w;
    o[4] = (__bf16)v1.x; o[5] = (__bf16)v1.y; o[6] = (__bf16)v1.z; o[7] = (__bf16)v1.w;
    *(bf16x8*)(outp + (size_t)8 * i) = o;
}

// -------- bf16 MFMA GEMM: per-(row, 16-col-group) max of sim ---------------
// grid (M/128, N/128), 256 threads = 4 waves (2x2), each wave 64x64 of C.
// Register-staged global->VGPR->ds_write_b128, LINEAR LDS [128][64] bf16.
// (Rounds 2/3 A/B-proved: this screen's output is identical to the swizzled
// global_load_lds variant.)
__global__ __launch_bounds__(256) void mfma_argmax_kernel(
    const unsigned short* __restrict__ Abf,
    const unsigned short* __restrict__ Bbf,
    const float* __restrict__ inv_t,
    float* __restrict__ sbest,   // [M][N/16]
    int M, int N) {
    __shared__ __align__(16) unsigned short sA[128 * 64];
    __shared__ __align__(16) unsigned short sB[128 * 64];
    const int tid = threadIdx.x;
    const int w = tid >> 6, l = tid & 63;
    const int wr = w >> 1, wc = w & 1;
    const int rowBase = blockIdx.x * 128;
    const int colBase = blockIdx.y * 128;
    const int ngroups = N >> 4;

    int goff[4], loff[4];
#pragma unroll
    for (int i = 0; i < 4; ++i) {
        int c = i * 256 + tid;
        goff[i] = (c >> 3) * DIM + (c & 7) * 8;  // ushort units
        loff[i] = c * 8;                          // ushort units
    }

    int aoff[2][4], boff[2][4];
#pragma unroll
    for (int s = 0; s < 2; ++s)
#pragma unroll
        for (int m = 0; m < 4; ++m) {
            int row = wr * 64 + m * 16 + (l & 15);
            aoff[s][m] = row * 128 + s * 64 + (l >> 4) * 16;
            int col = wc * 64 + m * 16 + (l & 15);
            boff[s][m] = col * 128 + s * 64 + (l >> 4) * 16;
        }

    f32x4 acc[4][4];
#pragma unroll
    for (int m = 0; m < 4; ++m)
#pragma unroll
        for (int n = 0; n < 4; ++n) acc[m][n] = (f32x4){0.f, 0.f, 0.f, 0.f};

    const unsigned short* ga0 = Abf + (size_t)rowBase * DIM;
    const unsigned short* gb0 = Bbf + (size_t)colBase * DIM;

    for (int kt = 0; kt < DIM / 64; ++kt) {
        const int kbase = kt * 64;
        u32x4 ra[4], rb[4];
#pragma unroll
        for (int i = 0; i < 4; ++i) {
            ra[i] = *(const u32x4*)(ga0 + kbase + goff[i]);
            rb[i] = *(const u32x4*)(gb0 + kbase + goff[i]);
        }
        __syncthreads();
#pragma unroll
        for (int i = 0; i < 4; ++i) {
            *(u32x4*)(&sA[loff[i]]) = ra[i];
            *(u32x4*)(&sB[loff[i]]) = rb[i];
        }
        __syncthreads();
#pragma unroll
        for (int s = 0; s < 2; ++s) {
            bf16x8 af[4], bfr[4];
#pragma unroll
            for (int m = 0; m < 4; ++m) {
                af[m] = *(const bf16x8*)((const char*)sA + aoff[s][m]);
                bfr[m] = *(const bf16x8*)((const char*)sB + boff[s][m]);
            }
#pragma unroll
            for (int m = 0; m < 4; ++m)
#pragma unroll
                for (int n = 0; n < 4; ++n)
                    acc[m][n] = __builtin_amdgcn_mfma_f32_16x16x32_bf16(
                        af[m], bfr[n], acc[m][n], 0, 0, 0);
        }
    }

    // C/D map (m89-verified): col = l&15, row = (l>>4)*4 + r.
#pragma unroll
    for (int n = 0; n < 4; ++n) {
        int col = colBase + wc * 64 + n * 16 + (l & 15);
        float it = inv_t[col];
#pragma unroll
        for (int m = 0; m < 4; ++m) {
#pragma unroll
            for (int r = 0; r < 4; ++r) {
                float v = acc[m][n][r] * it;
                v = fmaxf(v, __shfl_xor(v, 1, 64));
                v = fmaxf(v, __shfl_xor(v, 2, 64));
                v = fmaxf(v, __shfl_xor(v, 4, 64));
                v = fmaxf(v, __shfl_xor(v, 8, 64));
                if ((l & 15) == 0) {
                    int row = rowBase + wr * 64 + m * 16 + (l >> 4) * 4 + r;
                    int g = (colBase >> 4) + wc * 4 + n;
                    sbest[(size_t)row * ngroups + g] = v;
                }
            }
        }
    }
}

// ---------------- per-row max over groups -----------------------------------
__global__ void rowmax_kernel(const float* __restrict__ sbest,
                              float* __restrict__ rowbest, int M, int ngroups) {
    int row = blockIdx.x * 4 + (threadIdx.x >> 6);
    int l = threadIdx.x & 63;
    if (row >= M) return;
    const float* p = sbest + (size_t)row * ngroups;
    float v = -1e30f;
    for (int j = l; j < ngroups; j += 64) v = fmaxf(v, p[j]);
#pragma unroll
    for (int off = 32; off; off >>= 1) v = fmaxf(v, __shfl_xor(v, off, 64));
    if (l == 0) rowbest[row] = v;
}

// ---------------- flag candidate groups ------------------------------------
__global__ void flag_kernel(const float* __restrict__ sbest,
                            const float* __restrict__ rowbest,
                            int* __restrict__ cnt, int* __restrict__ slots,
                            int total, int ngroups) {
    int i = blockIdx.x * blockDim.x + threadIdx.x;
    if (i >= total) return;
    int row = i / ngroups;
    if (sbest[i] >= rowbest[row] - EPS) {
        int s = atomicAdd(&cnt[row], 1);
        if (s < MAXSLOTS) slots[row * MAXSLOTS + s] = i - row * ngroups;
    }
}

// ------- exact refine: sequential f32 fmaf chain per candidate column ------
__global__ __launch_bounds__(256) void refine_exact_kernel(
    const float* __restrict__ src, const float* __restrict__ tgt,
    const float* __restrict__ inv_t, const int* __restrict__ cnt,
    const int* __restrict__ slots, float* __restrict__ out, int M) {
    __shared__ __align__(16) float4 s_src[256];
    __shared__ float s_v[256];
    __shared__ int s_i[256];
    __shared__ int s_best;
    const int row = blockIdx.x;
    const int tid = threadIdx.x;
    s_src[tid] = ((const float4*)(src + (size_t)row * DIM))[tid];
    int m = cnt[row];
    if (m > MAXSLOTS) m = MAXSLOTS;
    const int ncand = m * GROUPW;
    float bv = -1e30f;
    int bi = 0x7fffffff;
    __syncthreads();
    for (int c = tid; c < ncand; c += 256) {
        int g = slots[row * MAXSLOTS + (c >> 4)];
        int col = g * GROUPW + (c & 15);
        const float4* trow = (const float4*)(tgt + (size_t)col * DIM);
        float acc = 0.f;
        for (int k4 = 0; k4 < 256; ++k4) {
            float4 a = s_src[k4];
            float4 b = trow[k4];
            acc = fmaf(a.x, b.x, acc);
            acc = fmaf(a.y, b.y, acc);
            acc = fmaf(a.z, b.z, acc);
            acc = fmaf(a.w, b.w, acc);
        }
        float v = acc * inv_t[col];
        if (v > bv || (v == bv && col < bi)) { bv = v; bi = col; }
    }
    s_v[tid] = bv;
    s_i[tid] = bi;
    __syncthreads();
    if (tid == 0) {
        float v = s_v[0];
        int ix = s_i[0];
        for (int t = 1; t < 256; ++t) {
            float v2 = s_v[t];
            int i2 = s_i[t];
            if (v2 > v || (v2 == v && i2 < ix)) { v = v2; ix = i2; }
        }
        s_best = ix;
    }
    __syncthreads();
    int ixb = s_best;
    ((float4*)(out + (size_t)row * DIM))[tid] =
        ((const float4*)(tgt + (size_t)ixb * DIM))[tid];
}

// ======================= fallback path (round-1, proven) ====================
__global__ __launch_bounds__(256) void fused_argmax_kernel(
    const float* __restrict__ A, const float* __restrict__ B,
    const float* __restrict__ inv_t, float* __restrict__ sbest,
    int* __restrict__ sidx, int M, int N) {
    __shared__ __align__(16) float sA[32][128 + PAD];
    __shared__ __align__(16) float sB[32][128 + PAD];
    const int tid = threadIdx.x;
    const int tx = tid & 15;
    const int ty = tid >> 4;
    const int rowBase = blockIdx.x * 128;
    const int stripe = blockIdx.y;
    const int stripeN = N / NSTRIPES;
    const int colBase0 = stripe * stripeN;
    const int lr = tid >> 3;
    const int lk = (tid & 7) << 2;
    float best[8];
    int bidx[8];
#pragma unroll
    for (int i = 0; i < 8; ++i) { best[i] = -1e30f; bidx[i] = 0; }
    for (int nt = 0; nt < stripeN / 128; ++nt) {
        const int colBase = colBase0 + nt * 128;
        float acc[8][8];
#pragma unroll
        for (int i = 0; i < 8; ++i)
#pragma unroll
            for (int j = 0; j < 8; ++j) acc[i][j] = 0.f;
        for (int kt = 0; kt < DIM / 32; ++kt) {
            const int k0 = kt * 32;
            __syncthreads();
#pragma unroll
            for (int p = 0; p < 4; ++p) {
                int r = lr + 32 * p;
                float4 va = *(const float4*)(A + (size_t)(rowBase + r) * DIM + k0 + lk);
                sA[lk + 0][r] = va.x; sA[lk + 1][r] = va.y;
                sA[lk + 2][r] = va.z; sA[lk + 3][r] = va.w;
                float4 vb = *(const float4*)(B + (size_t)(colBase + r) * DIM + k0 + lk);
                sB[lk + 0][r] = vb.x; sB[lk + 1][r] = vb.y;
                sB[lk + 2][r] = vb.z; sB[lk + 3][r] = vb.w;
            }
            __syncthreads();
#pragma unroll 4
            for (int k = 0; k < 32; ++k) {
                float4 af0 = *(const float4*)&sA[k][ty * 8];
                float4 af1 = *(const float4*)&sA[k][ty * 8 + 4];
                float4 bf0 = *(const float4*)&sB[k][tx * 8];
                float4 bf1 = *(const float4*)&sB[k][tx * 8 + 4];
                float a[8] = {af0.x, af0.y, af0.z, af0.w, af1.x, af1.y, af1.z, af1.w};
                float b[8] = {bf0.x, bf0.y, bf0.z, bf0.w, bf1.x, bf1.y, bf1.z, bf1.w};
#pragma unroll
                for (int i = 0; i < 8; ++i)
#pragma unroll
                    for (int j = 0; j < 8; ++j)
                        acc[i][j] = fmaf(a[i], b[j], acc[i][j]);
            }
        }
#pragma unroll
        for (int j = 0; j < 8; ++j) {
            int col = colBase + tx * 8 + j;
            float it = inv_t[col];
#pragma unroll
            for (int i = 0; i < 8; ++i) {
                float s = acc[i][j] * it;
                if (s > best[i]) { best[i] = s; bidx[i] = col; }
            }
        }
    }
#pragma unroll
    for (int i = 0; i < 8; ++i) {
        float v = best[i];
        int ix = bidx[i];
#pragma unroll
        for (int off = 1; off < 16; off <<= 1) {
            float v2 = __shfl_xor(v, off, 64);
            int ix2 = __shfl_xor(ix, off, 64);
            if (v2 > v || (v2 == v && ix2 < ix)) { v = v2; ix = ix2; }
        }
        if (tx == 0) {
            int row = rowBase + ty * 8 + i;
            sbest[(size_t)stripe * M + row] = v;
            sidx[(size_t)stripe * M + row] = ix;
        }
    }
}

__global__ void gather_kernel(const float* __restrict__ B,
                              const float* __restrict__ sbest,
                              const int* __restrict__ sidx,
                              float* __restrict__ out, int M) {
    int row = blockIdx.x;
    float v = -1e30f;
    int ix = 0;
#pragma unroll
    for (int s = 0; s < NSTRIPES; ++s) {
        float v2 = sbest[(size_t)s * M + row];
        int ix2 = sidx[(size_t)s * M + row];
        if (v2 > v || (v2 == v && ix2 < ix)) { v = v2; ix = ix2; }
    }
    const float4* srcp = (const float4*)(B + (size_t)ix * DIM);
    float4* dstp = (float4*)(out + (size_t)row * DIM);
    dstp[threadIdx.x] = srcp[threadIdx.x];
}

// ============================================================================
extern "C" void kernel_launch(void* const* d_in, const int* in_sizes, int n_in,
                              void* d_out, int out_size, void* d_ws, size_t ws_size,
                              hipStream_t stream) {
    const float* src = (const float*)d_in[0];
    const float* tgt = (const float*)d_in[1];
    float* out = (float*)d_out;
    int M = in_sizes[0] / DIM;
    int N = in_sizes[1] / DIM;
    int ngroups = N / GROUPW;

    auto align256 = [](size_t x) { return (x + 255) & ~(size_t)255; };
    size_t sz_invt = align256((size_t)N * 4);
    size_t sz_bfA = align256((size_t)M * DIM * 2);
    size_t sz_bfB = align256((size_t)N * DIM * 2);
    size_t sz_sbest = align256((size_t)M * ngroups * 4);
    size_t sz_rowbest = align256((size_t)M * 4);
    size_t sz_cnt = align256((size_t)M * 4);
    size_t sz_slots = align256((size_t)M * MAXSLOTS * 4);
    size_t need = sz_invt + sz_bfA + sz_bfB + sz_sbest + sz_rowbest + sz_cnt + sz_slots;

    if (ws_size >= need && (M % 128) == 0 && (N % 128) == 0) {
        char* p = (char*)d_ws;
        float* inv_t = (float*)p;                 p += sz_invt;
        unsigned short* bfA = (unsigned short*)p; p += sz_bfA;
        unsigned short* bfB = (unsigned short*)p; p += sz_bfB;
        float* sbest = (float*)p;                 p += sz_sbest;
        float* rowbest = (float*)p;               p += sz_rowbest;
        int* cnt = (int*)p;                       p += sz_cnt;
        int* slots = (int*)p;

        inv_norm_kernel<<<dim3((N + 3) / 4), 256, 0, stream>>>(tgt, inv_t, N);
        int n8a = M * DIM / 8, n8b = N * DIM / 8;
        convert_bf16_kernel<<<dim3((n8a + 255) / 256), 256, 0, stream>>>(src, bfA, n8a);
        convert_bf16_kernel<<<dim3((n8b + 255) / 256), 256, 0, stream>>>(tgt, bfB, n8b);
        mfma_argmax_kernel<<<dim3(M / 128, N / 128), 256, 0, stream>>>(
            bfA, bfB, inv_t, sbest, M, N);
        rowmax_kernel<<<dim3((M + 3) / 4), 256, 0, stream>>>(sbest, rowbest, M, ngroups);
        hipMemsetAsync(cnt, 0, (size_t)M * 4, stream);
        flag_kernel<<<dim3((M * ngroups + 255) / 256), 256, 0, stream>>>(
            sbest, rowbest, cnt, slots, M * ngroups, ngroups);
        refine_exact_kernel<<<dim3(M), 256, 0, stream>>>(
            src, tgt, inv_t, cnt, slots, out, M);
    } else {
        char* ws = (char*)d_ws;
        float* sbest = (float*)ws;
        int* sidx = (int*)(ws + (size_t)NSTRIPES * M * sizeof(float));
        float* inv_t = (float*)(ws + (size_t)NSTRIPES * M * (sizeof(float) + sizeof(int)));
        inv_norm_kernel<<<dim3((N + 3) / 4), 256, 0, stream>>>(tgt, inv_t, N);
        fused_argmax_kernel<<<dim3(M / 128, NSTRIPES), 256, 0, stream>>>(
            src, tgt, inv_t, sbest, sidx, M, N);
        gather_kernel<<<dim3(M), 256, 0, stream>>>(tgt, sbest, sidx, out, M);
    }
}

// Round 6
// 364.833 us; speedup vs baseline: 4.7176x; 1.4750x over previous
//
#include <hip/hip_runtime.h>
#include <math.h>

#define DIM      1024
#define NSTRIPES 16     // fallback path only
#define PAD      4
#define GROUPW   16
#define MAXSLOTS 32
// Screen values are dot*inv_t = |src_row| * cos_sim (|src_row| ~ 32): bf16
// screen noise sigma ~= 1.6e-3 in SCREEN units; EPS = 0.08 ~= 35 sigma.
// Verified: round-5 passed with absmax 0 at this EPS.
#define EPS      0.08f

typedef __attribute__((ext_vector_type(8))) __bf16 bf16x8;
typedef __attribute__((ext_vector_type(4))) __bf16 bf16x4;
typedef __attribute__((ext_vector_type(4))) float f32x4;

__device__ __forceinline__ void async16(void* lds, const void* g) {
    __builtin_amdgcn_global_load_lds(
        (const __attribute__((address_space(1))) unsigned int*)g,
        (__attribute__((address_space(3))) unsigned int*)lds, 16, 0, 0);
}

// ---------------- f32 -> bf16 conversion of source (8 elems/thread) --------
__global__ void convertA_kernel(const float* __restrict__ in,
                                unsigned short* __restrict__ outp, int n8) {
    int i = blockIdx.x * blockDim.x + threadIdx.x;
    if (i >= n8) return;
    const float4* p = (const float4*)in;
    float4 v0 = p[2 * i], v1 = p[2 * i + 1];
    bf16x8 o;
    o[0] = (__bf16)v0.x; o[1] = (__bf16)v0.y; o[2] = (__bf16)v0.z; o[3] = (__bf16)v0.w;
    o[4] = (__bf16)v1.x; o[5] = (__bf16)v1.y; o[6] = (__bf16)v1.z; o[7] = (__bf16)v1.w;
    *(bf16x8*)(outp + (size_t)8 * i) = o;
}

// ------- fused: target f32 -> bf16 AND inverse L2 norm (1 wave / row) ------
__global__ void convertB_norm_kernel(const float* __restrict__ tgt,
                                     unsigned short* __restrict__ bfB,
                                     float* __restrict__ inv_t, int n) {
    int row = blockIdx.x * 4 + (threadIdx.x >> 6);
    int l = threadIdx.x & 63;
    if (row >= n) return;
    const float4* rp = (const float4*)(tgt + (size_t)row * DIM);
    unsigned short* wp = bfB + (size_t)row * DIM;
    float ss = 0.f;
#pragma unroll
    for (int p = 0; p < 4; ++p) {
        float4 v = rp[l + 64 * p];
        bf16x4 o;
        o[0] = (__bf16)v.x; o[1] = (__bf16)v.y;
        o[2] = (__bf16)v.z; o[3] = (__bf16)v.w;
        *(bf16x4*)(wp + (size_t)(l + 64 * p) * 4) = o;
        ss = fmaf(v.x, v.x, ss);
        ss = fmaf(v.y, v.y, ss);
        ss = fmaf(v.z, v.z, ss);
        ss = fmaf(v.w, v.w, ss);
    }
#pragma unroll
    for (int off = 32; off; off >>= 1) ss += __shfl_xor(ss, off, 64);
    if (l == 0) inv_t[row] = 1.0f / fmaxf(sqrtf(ss), 1e-12f);
}

// -------- bf16 MFMA GEMM screen: per-(row, 16-col-group) max of sim --------
// grid (M/128, N/128), 256 threads = 4 waves (2x2), each wave 64x64 of C.
// Staging: global_load_lds width=16 with both-sides XOR swizzle (rule 21):
// LDS slot (row, c) holds global k-chunk (c ^ (row&7)); ds_read applies the
// same involution. Bit-identical output to reg-staged linear variant
// (A/B-proven rounds 2 vs 3).
__global__ __launch_bounds__(256) void mfma_argmax_kernel(
    const unsigned short* __restrict__ Abf,
    const unsigned short* __restrict__ Bbf,
    const float* __restrict__ inv_t,
    float* __restrict__ sbest,   // [M][N/16]
    int M, int N) {
    __shared__ __align__(16) unsigned short sA[128 * 64];
    __shared__ __align__(16) unsigned short sB[128 * 64];
    const int tid = threadIdx.x;
    const int w = tid >> 6, l = tid & 63;
    const int wr = w >> 1, wc = w & 1;
    const int rowBase = blockIdx.x * 128;
    const int colBase = blockIdx.y * 128;
    const int ngroups = N >> 4;

    // staging: 4 x 16B chunks per thread per matrix per K-tile
    size_t goff[4];
    int ldsoff[4];
#pragma unroll
    for (int i = 0; i < 4; ++i) {
        int chunk = (w * 4 + i) * 64 + l;
        int row = chunk >> 3, c = chunk & 7;
        int csrc = c ^ (row & 7);
        goff[i] = (size_t)row * DIM + csrc * 8;  // ushort units
        ldsoff[i] = (w * 4 + i) * 512;           // wave-uniform base (ushort)
    }

    // swizzled ds_read byte offsets (the same involution)
    int aoff[2][4], boff[2][4];
#pragma unroll
    for (int s = 0; s < 2; ++s)
#pragma unroll
        for (int m = 0; m < 4; ++m) {
            int row = wr * 64 + m * 16 + (l & 15);
            aoff[s][m] = (row * 128 + s * 64 + (l >> 4) * 16) ^ ((row & 7) << 4);
            int col = wc * 64 + m * 16 + (l & 15);
            boff[s][m] = (col * 128 + s * 64 + (l >> 4) * 16) ^ ((col & 7) << 4);
        }

    f32x4 acc[4][4];
#pragma unroll
    for (int m = 0; m < 4; ++m)
#pragma unroll
        for (int n = 0; n < 4; ++n) acc[m][n] = (f32x4){0.f, 0.f, 0.f, 0.f};

    const unsigned short* ga0 = Abf + (size_t)rowBase * DIM;
    const unsigned short* gb0 = Bbf + (size_t)colBase * DIM;

    for (int kt = 0; kt < DIM / 64; ++kt) {
        const unsigned short* ga = ga0 + kt * 64;
        const unsigned short* gb = gb0 + kt * 64;
#pragma unroll
        for (int i = 0; i < 4; ++i) {
            async16(&sA[ldsoff[i]], ga + goff[i]);
            async16(&sB[ldsoff[i]], gb + goff[i]);
        }
        __syncthreads();  // compiler drains vmcnt before s_barrier
#pragma unroll
        for (int s = 0; s < 2; ++s) {
            bf16x8 af[4], bfr[4];
#pragma unroll
            for (int m = 0; m < 4; ++m) {
                af[m] = *(const bf16x8*)((const char*)sA + aoff[s][m]);
                bfr[m] = *(const bf16x8*)((const char*)sB + boff[s][m]);
            }
#pragma unroll
            for (int m = 0; m < 4; ++m)
#pragma unroll
                for (int n = 0; n < 4; ++n)
                    acc[m][n] = __builtin_amdgcn_mfma_f32_16x16x32_bf16(
                        af[m], bfr[n], acc[m][n], 0, 0, 0);
        }
        __syncthreads();  // protect LDS before next stage
    }

    // epilogue: sim = acc * inv_t[col]; max over each 16-col fragment.
    // C/D map (m89-verified): col = l&15, row = (l>>4)*4 + r.
#pragma unroll
    for (int n = 0; n < 4; ++n) {
        int col = colBase + wc * 64 + n * 16 + (l & 15);
        float it = inv_t[col];
#pragma unroll
        for (int m = 0; m < 4; ++m) {
#pragma unroll
            for (int r = 0; r < 4; ++r) {
                float v = acc[m][n][r] * it;
                v = fmaxf(v, __shfl_xor(v, 1, 64));
                v = fmaxf(v, __shfl_xor(v, 2, 64));
                v = fmaxf(v, __shfl_xor(v, 4, 64));
                v = fmaxf(v, __shfl_xor(v, 8, 64));
                if ((l & 15) == 0) {
                    int row = rowBase + wr * 64 + m * 16 + (l >> 4) * 4 + r;
                    int g = (colBase >> 4) + wc * 4 + n;
                    sbest[(size_t)row * ngroups + g] = v;
                }
            }
        }
    }
}

// ------- fused per-row: max over groups + flag candidates (1 block/row) ----
__global__ __launch_bounds__(256) void rowflag_kernel(
    const float* __restrict__ sbest, int* __restrict__ cnt,
    int* __restrict__ slots, int ngroups) {
    const int row = blockIdx.x;
    const int tid = threadIdx.x;
    const int w = tid >> 6, l = tid & 63;
    __shared__ float wmax[4];
    __shared__ int scnt;
    const float* p = sbest + (size_t)row * ngroups;
    // each thread owns groups tid and tid+256 (ngroups = 512 at N=8192)
    float v0 = (tid < ngroups) ? p[tid] : -1e30f;
    float v1 = (tid + 256 < ngroups) ? p[tid + 256] : -1e30f;
    float v = fmaxf(v0, v1);
#pragma unroll
    for (int off = 32; off; off >>= 1) v = fmaxf(v, __shfl_xor(v, off, 64));
    if (l == 0) wmax[w] = v;
    if (tid == 0) scnt = 0;
    __syncthreads();
    float rmax = fmaxf(fmaxf(wmax[0], wmax[1]), fmaxf(wmax[2], wmax[3]));
    float thr = rmax - EPS;
    if (v0 >= thr) {
        int s = atomicAdd(&scnt, 1);
        if (s < MAXSLOTS) slots[row * MAXSLOTS + s] = tid;
    }
    if (v1 >= thr) {
        int s = atomicAdd(&scnt, 1);
        if (s < MAXSLOTS) slots[row * MAXSLOTS + s] = tid + 256;
    }
    __syncthreads();
    if (tid == 0) cnt[row] = scnt;
}

// ------- exact f32 refine (16 lanes/candidate) + argmax + gather -----------
__global__ __launch_bounds__(256) void refine_gather_kernel(
    const float* __restrict__ src, const float* __restrict__ tgt,
    const float* __restrict__ inv_t, const int* __restrict__ cnt,
    const int* __restrict__ slots, float* __restrict__ out, int M) {
    __shared__ __align__(16) float4 s_src[256];
    __shared__ float s_wv[4];
    __shared__ int s_wi[4];
    __shared__ int s_best;
    const int row = blockIdx.x;
    const int tid = threadIdx.x;
    const int w = tid >> 6;
    const int grp = tid >> 4;   // 16 groups of 16 lanes
    const int ln = tid & 15;
    s_src[tid] = ((const float4*)(src + (size_t)row * DIM))[tid];
    int m = cnt[row];
    if (m > MAXSLOTS) m = MAXSLOTS;
    const int ncand = m * GROUPW;
    float bv = -1e30f;
    int bi = 0x7fffffff;
    __syncthreads();
    for (int c = grp; c < ncand; c += 16) {
        int g = slots[row * MAXSLOTS + (c >> 4)];
        int col = g * GROUPW + (c & 15);
        const float4* trow = (const float4*)(tgt + (size_t)col * DIM);
        float dot = 0.f;
#pragma unroll
        for (int j = 0; j < 16; ++j) {
            float4 a = s_src[ln + 16 * j];
            float4 b = trow[ln + 16 * j];
            dot = fmaf(a.x, b.x, dot);
            dot = fmaf(a.y, b.y, dot);
            dot = fmaf(a.z, b.z, dot);
            dot = fmaf(a.w, b.w, dot);
        }
        dot += __shfl_xor(dot, 1, 64);
        dot += __shfl_xor(dot, 2, 64);
        dot += __shfl_xor(dot, 4, 64);
        dot += __shfl_xor(dot, 8, 64);
        float vv = dot * inv_t[col];
        if (vv > bv || (vv == bv && col < bi)) { bv = vv; bi = col; }
    }
    // reduce across 4 groups within wave (lanes differ only by group)
#pragma unroll
    for (int off = 16; off <= 32; off <<= 1) {
        float v2 = __shfl_xor(bv, off, 64);
        int i2 = __shfl_xor(bi, off, 64);
        if (v2 > bv || (v2 == bv && i2 < bi)) { bv = v2; bi = i2; }
    }
    if ((tid & 63) == 0) { s_wv[w] = bv; s_wi[w] = bi; }
    __syncthreads();
    if (tid == 0) {
        float v = s_wv[0];
        int ix = s_wi[0];
#pragma unroll
        for (int t = 1; t < 4; ++t) {
            float v2 = s_wv[t];
            int i2 = s_wi[t];
            if (v2 > v || (v2 == v && i2 < ix)) { v = v2; ix = i2; }
        }
        s_best = ix;
    }
    __syncthreads();
    int ixb = s_best;
    ((float4*)(out + (size_t)row * DIM))[tid] =
        ((const float4*)(tgt + (size_t)ixb * DIM))[tid];
}

// ======================= fallback path (round-1, proven) ====================
__global__ void inv_norm_kernel(const float* __restrict__ t,
                                float* __restrict__ inv_t, int n) {
    int wave = (int)((blockIdx.x * blockDim.x + threadIdx.x) >> 6);
    int lane = threadIdx.x & 63;
    if (wave >= n) return;
    const float4* row = (const float4*)(t + (size_t)wave * DIM);
    float ss = 0.f;
#pragma unroll
    for (int p = 0; p < 4; ++p) {
        float4 v = row[lane + 64 * p];
        ss = fmaf(v.x, v.x, ss);
        ss = fmaf(v.y, v.y, ss);
        ss = fmaf(v.z, v.z, ss);
        ss = fmaf(v.w, v.w, ss);
    }
#pragma unroll
    for (int off = 32; off; off >>= 1) ss += __shfl_xor(ss, off, 64);
    if (lane == 0) inv_t[wave] = 1.0f / fmaxf(sqrtf(ss), 1e-12f);
}

__global__ __launch_bounds__(256) void fused_argmax_kernel(
    const float* __restrict__ A, const float* __restrict__ B,
    const float* __restrict__ inv_t, float* __restrict__ sbest,
    int* __restrict__ sidx, int M, int N) {
    __shared__ __align__(16) float sA[32][128 + PAD];
    __shared__ __align__(16) float sB[32][128 + PAD];
    const int tid = threadIdx.x;
    const int tx = tid & 15;
    const int ty = tid >> 4;
    const int rowBase = blockIdx.x * 128;
    const int stripe = blockIdx.y;
    const int stripeN = N / NSTRIPES;
    const int colBase0 = stripe * stripeN;
    const int lr = tid >> 3;
    const int lk = (tid & 7) << 2;
    float best[8];
    int bidx[8];
#pragma unroll
    for (int i = 0; i < 8; ++i) { best[i] = -1e30f; bidx[i] = 0; }
    for (int nt = 0; nt < stripeN / 128; ++nt) {
        const int colBase = colBase0 + nt * 128;
        float acc[8][8];
#pragma unroll
        for (int i = 0; i < 8; ++i)
#pragma unroll
            for (int j = 0; j < 8; ++j) acc[i][j] = 0.f;
        for (int kt = 0; kt < DIM / 32; ++kt) {
            const int k0 = kt * 32;
            __syncthreads();
#pragma unroll
            for (int p = 0; p < 4; ++p) {
                int r = lr + 32 * p;
                float4 va = *(const float4*)(A + (size_t)(rowBase + r) * DIM + k0 + lk);
                sA[lk + 0][r] = va.x; sA[lk + 1][r] = va.y;
                sA[lk + 2][r] = va.z; sA[lk + 3][r] = va.w;
                float4 vb = *(const float4*)(B + (size_t)(colBase + r) * DIM + k0 + lk);
                sB[lk + 0][r] = vb.x; sB[lk + 1][r] = vb.y;
                sB[lk + 2][r] = vb.z; sB[lk + 3][r] = vb.w;
            }
            __syncthreads();
#pragma unroll 4
            for (int k = 0; k < 32; ++k) {
                float4 af0 = *(const float4*)&sA[k][ty * 8];
                float4 af1 = *(const float4*)&sA[k][ty * 8 + 4];
                float4 bf0 = *(const float4*)&sB[k][tx * 8];
                float4 bf1 = *(const float4*)&sB[k][tx * 8 + 4];
                float a[8] = {af0.x, af0.y, af0.z, af0.w, af1.x, af1.y, af1.z, af1.w};
                float b[8] = {bf0.x, bf0.y, bf0.z, bf0.w, bf1.x, bf1.y, bf1.z, bf1.w};
#pragma unroll
                for (int i = 0; i < 8; ++i)
#pragma unroll
                    for (int j = 0; j < 8; ++j)
                        acc[i][j] = fmaf(a[i], b[j], acc[i][j]);
            }
        }
#pragma unroll
        for (int j = 0; j < 8; ++j) {
            int col = colBase + tx * 8 + j;
            float it = inv_t[col];
#pragma unroll
            for (int i = 0; i < 8; ++i) {
                float s = acc[i][j] * it;
                if (s > best[i]) { best[i] = s; bidx[i] = col; }
            }
        }
    }
#pragma unroll
    for (int i = 0; i < 8; ++i) {
        float v = best[i];
        int ix = bidx[i];
#pragma unroll
        for (int off = 1; off < 16; off <<= 1) {
            float v2 = __shfl_xor(v, off, 64);
            int ix2 = __shfl_xor(ix, off, 64);
            if (v2 > v || (v2 == v && ix2 < ix)) { v = v2; ix = ix2; }
        }
        if (tx == 0) {
            int row = rowBase + ty * 8 + i;
            sbest[(size_t)stripe * M + row] = v;
            sidx[(size_t)stripe * M + row] = ix;
        }
    }
}

__global__ void gather_kernel(const float* __restrict__ B,
                              const float* __restrict__ sbest,
                              const int* __restrict__ sidx,
                              float* __restrict__ out, int M) {
    int row = blockIdx.x;
    float v = -1e30f;
    int ix = 0;
#pragma unroll
    for (int s = 0; s < NSTRIPES; ++s) {
        float v2 = sbest[(size_t)s * M + row];
        int ix2 = sidx[(size_t)s * M + row];
        if (v2 > v || (v2 == v && ix2 < ix)) { v = v2; ix = ix2; }
    }
    const float4* srcp = (const float4*)(B + (size_t)ix * DIM);
    float4* dstp = (float4*)(out + (size_t)row * DIM);
    dstp[threadIdx.x] = srcp[threadIdx.x];
}

// ============================================================================
extern "C" void kernel_launch(void* const* d_in, const int* in_sizes, int n_in,
                              void* d_out, int out_size, void* d_ws, size_t ws_size,
                              hipStream_t stream) {
    const float* src = (const float*)d_in[0];
    const float* tgt = (const float*)d_in[1];
    float* out = (float*)d_out;
    int M = in_sizes[0] / DIM;
    int N = in_sizes[1] / DIM;
    int ngroups = N / GROUPW;

    auto align256 = [](size_t x) { return (x + 255) & ~(size_t)255; };
    size_t sz_invt = align256((size_t)N * 4);
    size_t sz_bfA = align256((size_t)M * DIM * 2);
    size_t sz_bfB = align256((size_t)N * DIM * 2);
    size_t sz_sbest = align256((size_t)M * ngroups * 4);
    size_t sz_cnt = align256((size_t)M * 4);
    size_t sz_slots = align256((size_t)M * MAXSLOTS * 4);
    size_t need = sz_invt + sz_bfA + sz_bfB + sz_sbest + sz_cnt + sz_slots;

    if (ws_size >= need && (M % 128) == 0 && (N % 128) == 0 && ngroups <= 512) {
        char* p = (char*)d_ws;
        float* inv_t = (float*)p;                 p += sz_invt;
        unsigned short* bfA = (unsigned short*)p; p += sz_bfA;
        unsigned short* bfB = (unsigned short*)p; p += sz_bfB;
        float* sbest = (float*)p;                 p += sz_sbest;
        int* cnt = (int*)p;                       p += sz_cnt;
        int* slots = (int*)p;

        int n8a = M * DIM / 8;
        convertA_kernel<<<dim3((n8a + 255) / 256), 256, 0, stream>>>(src, bfA, n8a);
        convertB_norm_kernel<<<dim3((N + 3) / 4), 256, 0, stream>>>(tgt, bfB, inv_t, N);
        mfma_argmax_kernel<<<dim3(M / 128, N / 128), 256, 0, stream>>>(
            bfA, bfB, inv_t, sbest, M, N);
        rowflag_kernel<<<dim3(M), 256, 0, stream>>>(sbest, cnt, slots, ngroups);
        refine_gather_kernel<<<dim3(M), 256, 0, stream>>>(
            src, tgt, inv_t, cnt, slots, out, M);
    } else {
        char* ws = (char*)d_ws;
        float* sbest = (float*)ws;
        int* sidx = (int*)(ws + (size_t)NSTRIPES * M * sizeof(float));
        float* inv_t = (float*)(ws + (size_t)NSTRIPES * M * (sizeof(float) + sizeof(int)));
        inv_norm_kernel<<<dim3((N + 3) / 4), 256, 0, stream>>>(tgt, inv_t, N);
        fused_argmax_kernel<<<dim3(M / 128, NSTRIPES), 256, 0, stream>>>(
            src, tgt, inv_t, sbest, sidx, M, N);
        gather_kernel<<<dim3(M), 256, 0, stream>>>(tgt, sbest, sidx, out, M);
    }
}

// Round 7
// 310.965 us; speedup vs baseline: 5.5348x; 1.1732x over previous
//
#include <hip/hip_runtime.h>
#include <math.h>

#define DIM      1024
#define NSTRIPES 16     // fallback path only
#define PAD      4
#define GROUPW   16
#define MAXSLOTS 32
// Screen values are dot*inv_t = |src_row| * cos_sim (|src_row| ~ 32): bf16
// screen noise sigma ~= 1.6e-3 in SCREEN units; EPS = 0.08 ~= 35 sigma.
// Verified: rounds 5/6 passed with absmax 0 at this EPS.
#define EPS      0.08f

typedef __attribute__((ext_vector_type(8))) __bf16 bf16x8;
typedef __attribute__((ext_vector_type(4))) __bf16 bf16x4;
typedef __attribute__((ext_vector_type(4))) float f32x4;

__device__ __forceinline__ void async16(void* lds, const void* g) {
    __builtin_amdgcn_global_load_lds(
        (const __attribute__((address_space(1))) unsigned int*)g,
        (__attribute__((address_space(3))) unsigned int*)lds, 16, 0, 0);
}

// ---------------- f32 -> bf16 conversion of source (8 elems/thread) --------
__global__ void convertA_kernel(const float* __restrict__ in,
                                unsigned short* __restrict__ outp, int n8) {
    int i = blockIdx.x * blockDim.x + threadIdx.x;
    if (i >= n8) return;
    const float4* p = (const float4*)in;
    float4 v0 = p[2 * i], v1 = p[2 * i + 1];
    bf16x8 o;
    o[0] = (__bf16)v0.x; o[1] = (__bf16)v0.y; o[2] = (__bf16)v0.z; o[3] = (__bf16)v0.w;
    o[4] = (__bf16)v1.x; o[5] = (__bf16)v1.y; o[6] = (__bf16)v1.z; o[7] = (__bf16)v1.w;
    *(bf16x8*)(outp + (size_t)8 * i) = o;
}

// ------- fused: target f32 -> bf16 AND inverse L2 norm (1 wave / row) ------
__global__ void convertB_norm_kernel(const float* __restrict__ tgt,
                                     unsigned short* __restrict__ bfB,
                                     float* __restrict__ inv_t, int n) {
    int row = blockIdx.x * 4 + (threadIdx.x >> 6);
    int l = threadIdx.x & 63;
    if (row >= n) return;
    const float4* rp = (const float4*)(tgt + (size_t)row * DIM);
    unsigned short* wp = bfB + (size_t)row * DIM;
    float ss = 0.f;
#pragma unroll
    for (int p = 0; p < 4; ++p) {
        float4 v = rp[l + 64 * p];
        bf16x4 o;
        o[0] = (__bf16)v.x; o[1] = (__bf16)v.y;
        o[2] = (__bf16)v.z; o[3] = (__bf16)v.w;
        *(bf16x4*)(wp + (size_t)(l + 64 * p) * 4) = o;
        ss = fmaf(v.x, v.x, ss);
        ss = fmaf(v.y, v.y, ss);
        ss = fmaf(v.z, v.z, ss);
        ss = fmaf(v.w, v.w, ss);
    }
#pragma unroll
    for (int off = 32; off; off >>= 1) ss += __shfl_xor(ss, off, 64);
    if (l == 0) inv_t[row] = 1.0f / fmaxf(sqrtf(ss), 1e-12f);
}

// -------- bf16 MFMA GEMM screen: per-(row, 16-col-group) max of sim --------
// grid (M/128, N/128), 256 threads = 4 waves (2x2), each wave 64x64 of C.
// K-loop identical to round 6 (global_load_lds + both-sides XOR swizzle).
// NEW: swapped MFMA operands mfma(B,A) -> C/D transpose puts each group's
// 16 cols into (reg, lane>>4): per-group max = 3 in-reg fmax + 2 shfl,
// replacing the 16-shfl reduce. Screen values bit-identical (products
// commute; HW K-order unchanged).
__global__ __launch_bounds__(256) void mfma_argmax_kernel(
    const unsigned short* __restrict__ Abf,
    const unsigned short* __restrict__ Bbf,
    const float* __restrict__ inv_t,
    float* __restrict__ sbest,   // [M][N/16]
    int M, int N) {
    __shared__ __align__(16) unsigned short sA[128 * 64];
    __shared__ __align__(16) unsigned short sB[128 * 64];
    const int tid = threadIdx.x;
    const int w = tid >> 6, l = tid & 63;
    const int wr = w >> 1, wc = w & 1;
    const int rowBase = blockIdx.x * 128;
    const int colBase = blockIdx.y * 128;
    const int ngroups = N >> 4;

    // staging: 4 x 16B chunks per thread per matrix per K-tile
    size_t goff[4];
    int ldsoff[4];
#pragma unroll
    for (int i = 0; i < 4; ++i) {
        int chunk = (w * 4 + i) * 64 + l;
        int row = chunk >> 3, c = chunk & 7;
        int csrc = c ^ (row & 7);
        goff[i] = (size_t)row * DIM + csrc * 8;  // ushort units
        ldsoff[i] = (w * 4 + i) * 512;           // wave-uniform base (ushort)
    }

    // swizzled ds_read byte offsets (the same involution)
    int aoff[2][4], boff[2][4];
#pragma unroll
    for (int s = 0; s < 2; ++s)
#pragma unroll
        for (int m = 0; m < 4; ++m) {
            int row = wr * 64 + m * 16 + (l & 15);
            aoff[s][m] = (row * 128 + s * 64 + (l >> 4) * 16) ^ ((row & 7) << 4);
            int col = wc * 64 + m * 16 + (l & 15);
            boff[s][m] = (col * 128 + s * 64 + (l >> 4) * 16) ^ ((col & 7) << 4);
        }

    f32x4 acc[4][4];
#pragma unroll
    for (int m = 0; m < 4; ++m)
#pragma unroll
        for (int n = 0; n < 4; ++n) acc[m][n] = (f32x4){0.f, 0.f, 0.f, 0.f};

    const unsigned short* ga0 = Abf + (size_t)rowBase * DIM;
    const unsigned short* gb0 = Bbf + (size_t)colBase * DIM;

    for (int kt = 0; kt < DIM / 64; ++kt) {
        const unsigned short* ga = ga0 + kt * 64;
        const unsigned short* gb = gb0 + kt * 64;
#pragma unroll
        for (int i = 0; i < 4; ++i) {
            async16(&sA[ldsoff[i]], ga + goff[i]);
            async16(&sB[ldsoff[i]], gb + goff[i]);
        }
        __syncthreads();  // compiler drains vmcnt before s_barrier
#pragma unroll
        for (int s = 0; s < 2; ++s) {
            bf16x8 af[4], bfr[4];
#pragma unroll
            for (int m = 0; m < 4; ++m) {
                af[m] = *(const bf16x8*)((const char*)sA + aoff[s][m]);
                bfr[m] = *(const bf16x8*)((const char*)sB + boff[s][m]);
            }
            // SWAPPED operands: D[tc][sr] (transposed) — values bit-identical
#pragma unroll
            for (int m = 0; m < 4; ++m)
#pragma unroll
                for (int n = 0; n < 4; ++n)
                    acc[m][n] = __builtin_amdgcn_mfma_f32_16x16x32_bf16(
                        bfr[n], af[m], acc[m][n], 0, 0, 0);
        }
        __syncthreads();  // protect LDS before next stage
    }

    // epilogue (swapped C/D map): for acc[m][n]:
    //   source row  sr = rowBase + wr*64 + m*16 + (l&15)
    //   target col  tc = colBase + wc*64 + n*16 + (l>>4)*4 + r
    // group g = n-fragment == exactly one 16-col group. Max over tc =
    // max over r (in-reg) then over l>>4 (shfl 16,32).
    const int gBase = (colBase >> 4) + wc * 4;
    float4 it4[4];
#pragma unroll
    for (int n = 0; n < 4; ++n)
        it4[n] = *(const float4*)&inv_t[colBase + wc * 64 + n * 16 + ((l >> 4) << 2)];
#pragma unroll
    for (int n = 0; n < 4; ++n) {
#pragma unroll
        for (int m = 0; m < 4; ++m) {
            float v = acc[m][n][0] * it4[n].x;
            v = fmaxf(v, acc[m][n][1] * it4[n].y);
            v = fmaxf(v, acc[m][n][2] * it4[n].z);
            v = fmaxf(v, acc[m][n][3] * it4[n].w);
            v = fmaxf(v, __shfl_xor(v, 16, 64));
            v = fmaxf(v, __shfl_xor(v, 32, 64));
            if (l < 16) {
                int row = rowBase + wr * 64 + m * 16 + l;
                sbest[(size_t)row * ngroups + gBase + n] = v;
            }
        }
    }
}

// ------- fused per-row: max over groups + flag candidates (1 block/row) ----
__global__ __launch_bounds__(256) void rowflag_kernel(
    const float* __restrict__ sbest, int* __restrict__ cnt,
    int* __restrict__ slots, int ngroups) {
    const int row = blockIdx.x;
    const int tid = threadIdx.x;
    const int w = tid >> 6, l = tid & 63;
    __shared__ float wmax[4];
    __shared__ int scnt;
    const float* p = sbest + (size_t)row * ngroups;
    // each thread owns groups tid and tid+256 (ngroups = 512 at N=8192)
    float v0 = (tid < ngroups) ? p[tid] : -1e30f;
    float v1 = (tid + 256 < ngroups) ? p[tid + 256] : -1e30f;
    float v = fmaxf(v0, v1);
#pragma unroll
    for (int off = 32; off; off >>= 1) v = fmaxf(v, __shfl_xor(v, off, 64));
    if (l == 0) wmax[w] = v;
    if (tid == 0) scnt = 0;
    __syncthreads();
    float rmax = fmaxf(fmaxf(wmax[0], wmax[1]), fmaxf(wmax[2], wmax[3]));
    float thr = rmax - EPS;
    if (v0 >= thr) {
        int s = atomicAdd(&scnt, 1);
        if (s < MAXSLOTS) slots[row * MAXSLOTS + s] = tid;
    }
    if (v1 >= thr) {
        int s = atomicAdd(&scnt, 1);
        if (s < MAXSLOTS) slots[row * MAXSLOTS + s] = tid + 256;
    }
    __syncthreads();
    if (tid == 0) cnt[row] = scnt;
}

// ------- exact f32 refine (16 lanes/candidate) + argmax + gather -----------
__global__ __launch_bounds__(256) void refine_gather_kernel(
    const float* __restrict__ src, const float* __restrict__ tgt,
    const float* __restrict__ inv_t, const int* __restrict__ cnt,
    const int* __restrict__ slots, float* __restrict__ out, int M) {
    __shared__ __align__(16) float4 s_src[256];
    __shared__ float s_wv[4];
    __shared__ int s_wi[4];
    __shared__ int s_best;
    const int row = blockIdx.x;
    const int tid = threadIdx.x;
    const int w = tid >> 6;
    const int grp = tid >> 4;   // 16 groups of 16 lanes
    const int ln = tid & 15;
    s_src[tid] = ((const float4*)(src + (size_t)row * DIM))[tid];
    int m = cnt[row];
    if (m > MAXSLOTS) m = MAXSLOTS;
    const int ncand = m * GROUPW;
    float bv = -1e30f;
    int bi = 0x7fffffff;
    __syncthreads();
    for (int c = grp; c < ncand; c += 16) {
        int g = slots[row * MAXSLOTS + (c >> 4)];
        int col = g * GROUPW + (c & 15);
        const float4* trow = (const float4*)(tgt + (size_t)col * DIM);
        float dot = 0.f;
#pragma unroll
        for (int j = 0; j < 16; ++j) {
            float4 a = s_src[ln + 16 * j];
            float4 b = trow[ln + 16 * j];
            dot = fmaf(a.x, b.x, dot);
            dot = fmaf(a.y, b.y, dot);
            dot = fmaf(a.z, b.z, dot);
            dot = fmaf(a.w, b.w, dot);
        }
        dot += __shfl_xor(dot, 1, 64);
        dot += __shfl_xor(dot, 2, 64);
        dot += __shfl_xor(dot, 4, 64);
        dot += __shfl_xor(dot, 8, 64);
        float vv = dot * inv_t[col];
        if (vv > bv || (vv == bv && col < bi)) { bv = vv; bi = col; }
    }
    // reduce across 4 groups within wave (lanes differ only by group)
#pragma unroll
    for (int off = 16; off <= 32; off <<= 1) {
        float v2 = __shfl_xor(bv, off, 64);
        int i2 = __shfl_xor(bi, off, 64);
        if (v2 > bv || (v2 == bv && i2 < bi)) { bv = v2; bi = i2; }
    }
    if ((tid & 63) == 0) { s_wv[w] = bv; s_wi[w] = bi; }
    __syncthreads();
    if (tid == 0) {
        float v = s_wv[0];
        int ix = s_wi[0];
#pragma unroll
        for (int t = 1; t < 4; ++t) {
            float v2 = s_wv[t];
            int i2 = s_wi[t];
            if (v2 > v || (v2 == v && i2 < ix)) { v = v2; ix = i2; }
        }
        s_best = ix;
    }
    __syncthreads();
    int ixb = s_best;
    ((float4*)(out + (size_t)row * DIM))[tid] =
        ((const float4*)(tgt + (size_t)ixb * DIM))[tid];
}

// ======================= fallback path (round-1, proven) ====================
__global__ void inv_norm_kernel(const float* __restrict__ t,
                                float* __restrict__ inv_t, int n) {
    int wave = (int)((blockIdx.x * blockDim.x + threadIdx.x) >> 6);
    int lane = threadIdx.x & 63;
    if (wave >= n) return;
    const float4* row = (const float4*)(t + (size_t)wave * DIM);
    float ss = 0.f;
#pragma unroll
    for (int p = 0; p < 4; ++p) {
        float4 v = row[lane + 64 * p];
        ss = fmaf(v.x, v.x, ss);
        ss = fmaf(v.y, v.y, ss);
        ss = fmaf(v.z, v.z, ss);
        ss = fmaf(v.w, v.w, ss);
    }
#pragma unroll
    for (int off = 32; off; off >>= 1) ss += __shfl_xor(ss, off, 64);
    if (lane == 0) inv_t[wave] = 1.0f / fmaxf(sqrtf(ss), 1e-12f);
}

__global__ __launch_bounds__(256) void fused_argmax_kernel(
    const float* __restrict__ A, const float* __restrict__ B,
    const float* __restrict__ inv_t, float* __restrict__ sbest,
    int* __restrict__ sidx, int M, int N) {
    __shared__ __align__(16) float sA[32][128 + PAD];
    __shared__ __align__(16) float sB[32][128 + PAD];
    const int tid = threadIdx.x;
    const int tx = tid & 15;
    const int ty = tid >> 4;
    const int rowBase = blockIdx.x * 128;
    const int stripe = blockIdx.y;
    const int stripeN = N / NSTRIPES;
    const int colBase0 = stripe * stripeN;
    const int lr = tid >> 3;
    const int lk = (tid & 7) << 2;
    float best[8];
    int bidx[8];
#pragma unroll
    for (int i = 0; i < 8; ++i) { best[i] = -1e30f; bidx[i] = 0; }
    for (int nt = 0; nt < stripeN / 128; ++nt) {
        const int colBase = colBase0 + nt * 128;
        float acc[8][8];
#pragma unroll
        for (int i = 0; i < 8; ++i)
#pragma unroll
            for (int j = 0; j < 8; ++j) acc[i][j] = 0.f;
        for (int kt = 0; kt < DIM / 32; ++kt) {
            const int k0 = kt * 32;
            __syncthreads();
#pragma unroll
            for (int p = 0; p < 4; ++p) {
                int r = lr + 32 * p;
                float4 va = *(const float4*)(A + (size_t)(rowBase + r) * DIM + k0 + lk);
                sA[lk + 0][r] = va.x; sA[lk + 1][r] = va.y;
                sA[lk + 2][r] = va.z; sA[lk + 3][r] = va.w;
                float4 vb = *(const float4*)(B + (size_t)(colBase + r) * DIM + k0 + lk);
                sB[lk + 0][r] = vb.x; sB[lk + 1][r] = vb.y;
                sB[lk + 2][r] = vb.z; sB[lk + 3][r] = vb.w;
            }
            __syncthreads();
#pragma unroll 4
            for (int k = 0; k < 32; ++k) {
                float4 af0 = *(const float4*)&sA[k][ty * 8];
                float4 af1 = *(const float4*)&sA[k][ty * 8 + 4];
                float4 bf0 = *(const float4*)&sB[k][tx * 8];
                float4 bf1 = *(const float4*)&sB[k][tx * 8 + 4];
                float a[8] = {af0.x, af0.y, af0.z, af0.w, af1.x, af1.y, af1.z, af1.w};
                float b[8] = {bf0.x, bf0.y, bf0.z, bf0.w, bf1.x, bf1.y, bf1.z, bf1.w};
#pragma unroll
                for (int i = 0; i < 8; ++i)
#pragma unroll
                    for (int j = 0; j < 8; ++j)
                        acc[i][j] = fmaf(a[i], b[j], acc[i][j]);
            }
        }
#pragma unroll
        for (int j = 0; j < 8; ++j) {
            int col = colBase + tx * 8 + j;
            float it = inv_t[col];
#pragma unroll
            for (int i = 0; i < 8; ++i) {
                float s = acc[i][j] * it;
                if (s > best[i]) { best[i] = s; bidx[i] = col; }
            }
        }
    }
#pragma unroll
    for (int i = 0; i < 8; ++i) {
        float v = best[i];
        int ix = bidx[i];
#pragma unroll
        for (int off = 1; off < 16; off <<= 1) {
            float v2 = __shfl_xor(v, off, 64);
            int ix2 = __shfl_xor(ix, off, 64);
            if (v2 > v || (v2 == v && ix2 < ix)) { v = v2; ix = ix2; }
        }
        if (tx == 0) {
            int row = rowBase + ty * 8 + i;
            sbest[(size_t)stripe * M + row] = v;
            sidx[(size_t)stripe * M + row] = ix;
        }
    }
}

__global__ void gather_kernel(const float* __restrict__ B,
                              const float* __restrict__ sbest,
                              const int* __restrict__ sidx,
                              float* __restrict__ out, int M) {
    int row = blockIdx.x;
    float v = -1e30f;
    int ix = 0;
#pragma unroll
    for (int s = 0; s < NSTRIPES; ++s) {
        float v2 = sbest[(size_t)s * M + row];
        int ix2 = sidx[(size_t)s * M + row];
        if (v2 > v || (v2 == v && ix2 < ix)) { v = v2; ix = ix2; }
    }
    const float4* srcp = (const float4*)(B + (size_t)ix * DIM);
    float4* dstp = (float4*)(out + (size_t)row * DIM);
    dstp[threadIdx.x] = srcp[threadIdx.x];
}

// ============================================================================
extern "C" void kernel_launch(void* const* d_in, const int* in_sizes, int n_in,
                              void* d_out, int out_size, void* d_ws, size_t ws_size,
                              hipStream_t stream) {
    const float* src = (const float*)d_in[0];
    const float* tgt = (const float*)d_in[1];
    float* out = (float*)d_out;
    int M = in_sizes[0] / DIM;
    int N = in_sizes[1] / DIM;
    int ngroups = N / GROUPW;

    auto align256 = [](size_t x) { return (x + 255) & ~(size_t)255; };
    size_t sz_invt = align256((size_t)N * 4);
    size_t sz_bfA = align256((size_t)M * DIM * 2);
    size_t sz_bfB = align256((size_t)N * DIM * 2);
    size_t sz_sbest = align256((size_t)M * ngroups * 4);
    size_t sz_cnt = align256((size_t)M * 4);
    size_t sz_slots = align256((size_t)M * MAXSLOTS * 4);
    size_t need = sz_invt + sz_bfA + sz_bfB + sz_sbest + sz_cnt + sz_slots;

    if (ws_size >= need && (M % 128) == 0 && (N % 128) == 0 && ngroups <= 512) {
        char* p = (char*)d_ws;
        float* inv_t = (float*)p;                 p += sz_invt;
        unsigned short* bfA = (unsigned short*)p; p += sz_bfA;
        unsigned short* bfB = (unsigned short*)p; p += sz_bfB;
        float* sbest = (float*)p;                 p += sz_sbest;
        int* cnt = (int*)p;                       p += sz_cnt;
        int* slots = (int*)p;

        int n8a = M * DIM / 8;
        convertA_kernel<<<dim3((n8a + 255) / 256), 256, 0, stream>>>(src, bfA, n8a);
        convertB_norm_kernel<<<dim3((N + 3) / 4), 256, 0, stream>>>(tgt, bfB, inv_t, N);
        mfma_argmax_kernel<<<dim3(M / 128, N / 128), 256, 0, stream>>>(
            bfA, bfB, inv_t, sbest, M, N);
        rowflag_kernel<<<dim3(M), 256, 0, stream>>>(sbest, cnt, slots, ngroups);
        refine_gather_kernel<<<dim3(M), 256, 0, stream>>>(
            src, tgt, inv_t, cnt, slots, out, M);
    } else {
        char* ws = (char*)d_ws;
        float* sbest = (float*)ws;
        int* sidx = (int*)(ws + (size_t)NSTRIPES * M * sizeof(float));
        float* inv_t = (float*)(ws + (size_t)NSTRIPES * M * (sizeof(float) + sizeof(int)));
        inv_norm_kernel<<<dim3((N + 3) / 4), 256, 0, stream>>>(tgt, inv_t, N);
        fused_argmax_kernel<<<dim3(M / 128, NSTRIPES), 256, 0, stream>>>(
            src, tgt, inv_t, sbest, sidx, M, N);
        gather_kernel<<<dim3(M), 256, 0, stream>>>(tgt, sbest, sidx, out, M);
    }
}

// Round 8
// 258.723 us; speedup vs baseline: 6.6524x; 1.2019x over previous
//
#include <hip/hip_runtime.h>
#include <math.h>

#define DIM      1024
#define NSTRIPES 16     // fallback path only
#define PAD      4
#define MAXSLOTS 32
// Screen values are dot*inv_t = |src_row| * cos_sim (|src_row| ~ 32): bf16
// screen noise sigma ~= 1.6e-3 in SCREEN units; EPS = 0.08 ~= 35 sigma.
// Verified: rounds 5/6/7 passed with absmax 0 at this EPS. The guarantee is
// group-width independent (true argmax col's own group max >= its value).
#define EPS      0.08f

typedef __attribute__((ext_vector_type(8))) __bf16 bf16x8;
typedef __attribute__((ext_vector_type(4))) __bf16 bf16x4;
typedef __attribute__((ext_vector_type(4))) float f32x4;

__device__ __forceinline__ void async16(void* lds, const void* g) {
    __builtin_amdgcn_global_load_lds(
        (const __attribute__((address_space(1))) unsigned int*)g,
        (__attribute__((address_space(3))) unsigned int*)lds, 16, 0, 0);
}

// ---------------- f32 -> bf16 conversion of source (8 elems/thread) --------
__global__ void convertA_kernel(const float* __restrict__ in,
                                unsigned short* __restrict__ outp, int n8) {
    int i = blockIdx.x * blockDim.x + threadIdx.x;
    if (i >= n8) return;
    const float4* p = (const float4*)in;
    float4 v0 = p[2 * i], v1 = p[2 * i + 1];
    bf16x8 o;
    o[0] = (__bf16)v0.x; o[1] = (__bf16)v0.y; o[2] = (__bf16)v0.z; o[3] = (__bf16)v0.w;
    o[4] = (__bf16)v1.x; o[5] = (__bf16)v1.y; o[6] = (__bf16)v1.z; o[7] = (__bf16)v1.w;
    *(bf16x8*)(outp + (size_t)8 * i) = o;
}

// ------- fused: target f32 -> bf16 AND inverse L2 norm (1 wave / row) ------
__global__ void convertB_norm_kernel(const float* __restrict__ tgt,
                                     unsigned short* __restrict__ bfB,
                                     float* __restrict__ inv_t, int n) {
    int row = blockIdx.x * 4 + (threadIdx.x >> 6);
    int l = threadIdx.x & 63;
    if (row >= n) return;
    const float4* rp = (const float4*)(tgt + (size_t)row * DIM);
    unsigned short* wp = bfB + (size_t)row * DIM;
    float ss = 0.f;
#pragma unroll
    for (int p = 0; p < 4; ++p) {
        float4 v = rp[l + 64 * p];
        bf16x4 o;
        o[0] = (__bf16)v.x; o[1] = (__bf16)v.y;
        o[2] = (__bf16)v.z; o[3] = (__bf16)v.w;
        *(bf16x4*)(wp + (size_t)(l + 64 * p) * 4) = o;
        ss = fmaf(v.x, v.x, ss);
        ss = fmaf(v.y, v.y, ss);
        ss = fmaf(v.z, v.z, ss);
        ss = fmaf(v.w, v.w, ss);
    }
#pragma unroll
    for (int off = 32; off; off >>= 1) ss += __shfl_xor(ss, off, 64);
    if (l == 0) inv_t[row] = 1.0f / fmaxf(sqrtf(ss), 1e-12f);
}

// -------- bf16 MFMA GEMM screen: per-(row, GW-col-group) max of sim --------
// grid (M/128, N/128), 256 threads = 4 waves (2x2), each wave 64x64 of C.
// NEW vs r7: 2-deep LDS double-buffer, stage for K-tile t+1 issued at loop
// top, ONE __syncthreads per K-tile (implicit vmcnt(0)+lgkmcnt(0) drain is
// exactly the dbuf invariant: reads of buf^1 done before barrier t-1, its
// new contents landed before barrier t). Swapped MFMA operands (r7-proven).
template <int GW>
__global__ __launch_bounds__(256) void mfma_argmax_kernel(
    const unsigned short* __restrict__ Abf,
    const unsigned short* __restrict__ Bbf,
    const float* __restrict__ inv_t,
    float* __restrict__ sbest,   // [M][N/GW]
    int M, int N) {
    __shared__ __align__(16) unsigned short sA[2][128 * 64];
    __shared__ __align__(16) unsigned short sB[2][128 * 64];
    const int tid = threadIdx.x;
    const int w = tid >> 6, l = tid & 63;
    const int wr = w >> 1, wc = w & 1;
    const int rowBase = blockIdx.x * 128;
    const int colBase = blockIdx.y * 128;
    const int ngroups = N / GW;

    // staging: 4 x 16B chunks per thread per matrix per K-tile, inverse-
    // swizzled global source + linear LDS dest (rule 21, r6/r7-proven)
    size_t goff[4];
    int ldsoff[4];
#pragma unroll
    for (int i = 0; i < 4; ++i) {
        int chunk = (w * 4 + i) * 64 + l;
        int row = chunk >> 3, c = chunk & 7;
        int csrc = c ^ (row & 7);
        goff[i] = (size_t)row * DIM + csrc * 8;  // ushort units
        ldsoff[i] = (w * 4 + i) * 512;           // wave-uniform base (ushort)
    }

    // swizzled ds_read byte offsets (same involution)
    int aoff[2][4], boff[2][4];
#pragma unroll
    for (int s = 0; s < 2; ++s)
#pragma unroll
        for (int m = 0; m < 4; ++m) {
            int row = wr * 64 + m * 16 + (l & 15);
            aoff[s][m] = (row * 128 + s * 64 + (l >> 4) * 16) ^ ((row & 7) << 4);
            int col = wc * 64 + m * 16 + (l & 15);
            boff[s][m] = (col * 128 + s * 64 + (l >> 4) * 16) ^ ((col & 7) << 4);
        }

    f32x4 acc[4][4];
#pragma unroll
    for (int m = 0; m < 4; ++m)
#pragma unroll
        for (int n = 0; n < 4; ++n) acc[m][n] = (f32x4){0.f, 0.f, 0.f, 0.f};

    const unsigned short* ga0 = Abf + (size_t)rowBase * DIM;
    const unsigned short* gb0 = Bbf + (size_t)colBase * DIM;

    const int NT = DIM / 64;

    // prologue: stage K-tile 0 into buf 0, drain
#pragma unroll
    for (int i = 0; i < 4; ++i) {
        async16(&sA[0][ldsoff[i]], ga0 + goff[i]);
        async16(&sB[0][ldsoff[i]], gb0 + goff[i]);
    }
    __syncthreads();

    for (int kt = 0; kt < NT - 1; ++kt) {
        const int cur = kt & 1;
        // stage K-tile kt+1 into the other buffer (flight overlaps compute)
        const unsigned short* ga = ga0 + (kt + 1) * 64;
        const unsigned short* gb = gb0 + (kt + 1) * 64;
#pragma unroll
        for (int i = 0; i < 4; ++i) {
            async16(&sA[cur ^ 1][ldsoff[i]], ga + goff[i]);
            async16(&sB[cur ^ 1][ldsoff[i]], gb + goff[i]);
        }
        // compute on buf[cur]
#pragma unroll
        for (int s = 0; s < 2; ++s) {
            bf16x8 af[4], bfr[4];
#pragma unroll
            for (int m = 0; m < 4; ++m) {
                af[m] = *(const bf16x8*)((const char*)&sA[cur][0] + aoff[s][m]);
                bfr[m] = *(const bf16x8*)((const char*)&sB[cur][0] + boff[s][m]);
            }
#pragma unroll
            for (int m = 0; m < 4; ++m)
#pragma unroll
                for (int n = 0; n < 4; ++n)
                    acc[m][n] = __builtin_amdgcn_mfma_f32_16x16x32_bf16(
                        bfr[n], af[m], acc[m][n], 0, 0, 0);
        }
        __syncthreads();  // drains vmcnt(0)+lgkmcnt(0): buf[cur^1] ready,
                          // all reads of buf[cur] complete block-wide
    }
    {   // last K-tile: compute only
        const int cur = (NT - 1) & 1;
#pragma unroll
        for (int s = 0; s < 2; ++s) {
            bf16x8 af[4], bfr[4];
#pragma unroll
            for (int m = 0; m < 4; ++m) {
                af[m] = *(const bf16x8*)((const char*)&sA[cur][0] + aoff[s][m]);
                bfr[m] = *(const bf16x8*)((const char*)&sB[cur][0] + boff[s][m]);
            }
#pragma unroll
            for (int m = 0; m < 4; ++m)
#pragma unroll
                for (int n = 0; n < 4; ++n)
                    acc[m][n] = __builtin_amdgcn_mfma_f32_16x16x32_bf16(
                        bfr[n], af[m], acc[m][n], 0, 0, 0);
        }
    }

    // epilogue (swapped C/D map, r7-verified): acc[m][n][r]:
    //   source row sr = rowBase + wr*64 + m*16 + (l&15)
    //   target col tc = colBase + wc*64 + n*16 + (l>>4)*4 + r
    const int q = l >> 4;
    float4 it4[4];
#pragma unroll
    for (int n = 0; n < 4; ++n)
        it4[n] = *(const float4*)&inv_t[colBase + wc * 64 + n * 16 + (q << 2)];
#pragma unroll
    for (int n = 0; n < 4; ++n) {
#pragma unroll
        for (int m = 0; m < 4; ++m) {
            float v = acc[m][n][0] * it4[n].x;
            v = fmaxf(v, acc[m][n][1] * it4[n].y);
            v = fmaxf(v, acc[m][n][2] * it4[n].z);
            v = fmaxf(v, acc[m][n][3] * it4[n].w);
            if constexpr (GW == 16) {
                v = fmaxf(v, __shfl_xor(v, 16, 64));
                v = fmaxf(v, __shfl_xor(v, 32, 64));
                if (l < 16) {
                    int row = rowBase + wr * 64 + m * 16 + l;
                    int g = (colBase >> 4) + wc * 4 + n;
                    sbest[(size_t)row * ngroups + g] = v;
                }
            } else {  // GW == 8: group = 8 cols = {q,q^1} x r
                v = fmaxf(v, __shfl_xor(v, 16, 64));
                if ((l & 16) == 0) {
                    int row = rowBase + wr * 64 + m * 16 + (l & 15);
                    int g = (colBase >> 3) + wc * 8 + n * 2 + (q >> 1);
                    sbest[(size_t)row * ngroups + g] = v;
                }
            }
        }
    }
}

// --- fused per-row: rowmax + flag + exact f32 refine + gather (1 blk/row) --
__global__ __launch_bounds__(256) void flag_refine_kernel(
    const float* __restrict__ sbest, const float* __restrict__ src,
    const float* __restrict__ tgt, const float* __restrict__ inv_t,
    float* __restrict__ out, int ngroups, int gsh) {
    __shared__ __align__(16) float4 s_src[256];
    __shared__ float wmax[4];
    __shared__ int s_slots[MAXSLOTS];
    __shared__ int s_cnt;
    __shared__ float s_wv[4];
    __shared__ int s_wi[4];
    __shared__ int s_best;
    const int row = blockIdx.x;
    const int tid = threadIdx.x;
    const int w = tid >> 6, l = tid & 63;
    const int GW = 1 << gsh;

    s_src[tid] = ((const float4*)(src + (size_t)row * DIM))[tid];
    if (tid == 0) s_cnt = 0;

    // rowmax over groups (nper = ngroups/256, <= 4)
    const float* p = sbest + (size_t)row * ngroups;
    const int nper = ngroups >> 8;
    float v[4];
    float mx = -1e30f;
    for (int j = 0; j < nper; ++j) {
        v[j] = p[tid + j * 256];
        mx = fmaxf(mx, v[j]);
    }
#pragma unroll
    for (int off = 32; off; off >>= 1) mx = fmaxf(mx, __shfl_xor(mx, off, 64));
    if (l == 0) wmax[w] = mx;
    __syncthreads();
    float thr = fmaxf(fmaxf(wmax[0], wmax[1]), fmaxf(wmax[2], wmax[3])) - EPS;
    for (int j = 0; j < nper; ++j) {
        if (v[j] >= thr) {
            int s = atomicAdd(&s_cnt, 1);
            if (s < MAXSLOTS) s_slots[s] = tid + j * 256;
        }
    }
    __syncthreads();

    // exact f32 refine: 16 lanes per candidate column (r6/r7-proven)
    int m = s_cnt;
    if (m > MAXSLOTS) m = MAXSLOTS;
    const int ncand = m << gsh;
    const int grp = tid >> 4;
    const int ln = tid & 15;
    float bv = -1e30f;
    int bi = 0x7fffffff;
    for (int c = grp; c < ncand; c += 16) {
        int col = (s_slots[c >> gsh] << gsh) + (c & (GW - 1));
        const float4* trow = (const float4*)(tgt + (size_t)col * DIM);
        float dot = 0.f;
#pragma unroll
        for (int j = 0; j < 16; ++j) {
            float4 a = s_src[ln + 16 * j];
            float4 b = trow[ln + 16 * j];
            dot = fmaf(a.x, b.x, dot);
            dot = fmaf(a.y, b.y, dot);
            dot = fmaf(a.z, b.z, dot);
            dot = fmaf(a.w, b.w, dot);
        }
        dot += __shfl_xor(dot, 1, 64);
        dot += __shfl_xor(dot, 2, 64);
        dot += __shfl_xor(dot, 4, 64);
        dot += __shfl_xor(dot, 8, 64);
        float vv = dot * inv_t[col];
        if (vv > bv || (vv == bv && col < bi)) { bv = vv; bi = col; }
    }
#pragma unroll
    for (int off = 16; off <= 32; off <<= 1) {
        float v2 = __shfl_xor(bv, off, 64);
        int i2 = __shfl_xor(bi, off, 64);
        if (v2 > bv || (v2 == bv && i2 < bi)) { bv = v2; bi = i2; }
    }
    if (l == 0) { s_wv[w] = bv; s_wi[w] = bi; }
    __syncthreads();
    if (tid == 0) {
        float vv = s_wv[0];
        int ix = s_wi[0];
#pragma unroll
        for (int t = 1; t < 4; ++t) {
            float v2 = s_wv[t];
            int i2 = s_wi[t];
            if (v2 > vv || (v2 == vv && i2 < ix)) { vv = v2; ix = i2; }
        }
        s_best = ix;
    }
    __syncthreads();
    int ixb = s_best;
    ((float4*)(out + (size_t)row * DIM))[tid] =
        ((const float4*)(tgt + (size_t)ixb * DIM))[tid];
}

// ======================= fallback path (round-1, proven) ====================
__global__ void inv_norm_kernel(const float* __restrict__ t,
                                float* __restrict__ inv_t, int n) {
    int wave = (int)((blockIdx.x * blockDim.x + threadIdx.x) >> 6);
    int lane = threadIdx.x & 63;
    if (wave >= n) return;
    const float4* row = (const float4*)(t + (size_t)wave * DIM);
    float ss = 0.f;
#pragma unroll
    for (int p = 0; p < 4; ++p) {
        float4 v = row[lane + 64 * p];
        ss = fmaf(v.x, v.x, ss);
        ss = fmaf(v.y, v.y, ss);
        ss = fmaf(v.z, v.z, ss);
        ss = fmaf(v.w, v.w, ss);
    }
#pragma unroll
    for (int off = 32; off; off >>= 1) ss += __shfl_xor(ss, off, 64);
    if (lane == 0) inv_t[wave] = 1.0f / fmaxf(sqrtf(ss), 1e-12f);
}

__global__ __launch_bounds__(256) void fused_argmax_kernel(
    const float* __restrict__ A, const float* __restrict__ B,
    const float* __restrict__ inv_t, float* __restrict__ sbest,
    int* __restrict__ sidx, int M, int N) {
    __shared__ __align__(16) float sA[32][128 + PAD];
    __shared__ __align__(16) float sB[32][128 + PAD];
    const int tid = threadIdx.x;
    const int tx = tid & 15;
    const int ty = tid >> 4;
    const int rowBase = blockIdx.x * 128;
    const int stripe = blockIdx.y;
    const int stripeN = N / NSTRIPES;
    const int colBase0 = stripe * stripeN;
    const int lr = tid >> 3;
    const int lk = (tid & 7) << 2;
    float best[8];
    int bidx[8];
#pragma unroll
    for (int i = 0; i < 8; ++i) { best[i] = -1e30f; bidx[i] = 0; }
    for (int nt = 0; nt < stripeN / 128; ++nt) {
        const int colBase = colBase0 + nt * 128;
        float acc[8][8];
#pragma unroll
        for (int i = 0; i < 8; ++i)
#pragma unroll
            for (int j = 0; j < 8; ++j) acc[i][j] = 0.f;
        for (int kt = 0; kt < DIM / 32; ++kt) {
            const int k0 = kt * 32;
            __syncthreads();
#pragma unroll
            for (int p = 0; p < 4; ++p) {
                int r = lr + 32 * p;
                float4 va = *(const float4*)(A + (size_t)(rowBase + r) * DIM + k0 + lk);
                sA[lk + 0][r] = va.x; sA[lk + 1][r] = va.y;
                sA[lk + 2][r] = va.z; sA[lk + 3][r] = va.w;
                float4 vb = *(const float4*)(B + (size_t)(colBase + r) * DIM + k0 + lk);
                sB[lk + 0][r] = vb.x; sB[lk + 1][r] = vb.y;
                sB[lk + 2][r] = vb.z; sB[lk + 3][r] = vb.w;
            }
            __syncthreads();
#pragma unroll 4
            for (int k = 0; k < 32; ++k) {
                float4 af0 = *(const float4*)&sA[k][ty * 8];
                float4 af1 = *(const float4*)&sA[k][ty * 8 + 4];
                float4 bf0 = *(const float4*)&sB[k][tx * 8];
                float4 bf1 = *(const float4*)&sB[k][tx * 8 + 4];
                float a[8] = {af0.x, af0.y, af0.z, af0.w, af1.x, af1.y, af1.z, af1.w};
                float b[8] = {bf0.x, bf0.y, bf0.z, bf0.w, bf1.x, bf1.y, bf1.z, bf1.w};
#pragma unroll
                for (int i = 0; i < 8; ++i)
#pragma unroll
                    for (int j = 0; j < 8; ++j)
                        acc[i][j] = fmaf(a[i], b[j], acc[i][j]);
            }
        }
#pragma unroll
        for (int j = 0; j < 8; ++j) {
            int col = colBase + tx * 8 + j;
            float it = inv_t[col];
#pragma unroll
            for (int i = 0; i < 8; ++i) {
                float s = acc[i][j] * it;
                if (s > best[i]) { best[i] = s; bidx[i] = col; }
            }
        }
    }
#pragma unroll
    for (int i = 0; i < 8; ++i) {
        float v = best[i];
        int ix = bidx[i];
#pragma unroll
        for (int off = 1; off < 16; off <<= 1) {
            float v2 = __shfl_xor(v, off, 64);
            int ix2 = __shfl_xor(ix, off, 64);
            if (v2 > v || (v2 == v && ix2 < ix)) { v = v2; ix = ix2; }
        }
        if (tx == 0) {
            int row = rowBase + ty * 8 + i;
            sbest[(size_t)stripe * M + row] = v;
            sidx[(size_t)stripe * M + row] = ix;
        }
    }
}

__global__ void gather_kernel(const float* __restrict__ B,
                              const float* __restrict__ sbest,
                              const int* __restrict__ sidx,
                              float* __restrict__ out, int M) {
    int row = blockIdx.x;
    float v = -1e30f;
    int ix = 0;
#pragma unroll
    for (int s = 0; s < NSTRIPES; ++s) {
        float v2 = sbest[(size_t)s * M + row];
        int ix2 = sidx[(size_t)s * M + row];
        if (v2 > v || (v2 == v && ix2 < ix)) { v = v2; ix = ix2; }
    }
    const float4* srcp = (const float4*)(B + (size_t)ix * DIM);
    float4* dstp = (float4*)(out + (size_t)row * DIM);
    dstp[threadIdx.x] = srcp[threadIdx.x];
}

// ============================================================================
extern "C" void kernel_launch(void* const* d_in, const int* in_sizes, int n_in,
                              void* d_out, int out_size, void* d_ws, size_t ws_size,
                              hipStream_t stream) {
    const float* src = (const float*)d_in[0];
    const float* tgt = (const float*)d_in[1];
    float* out = (float*)d_out;
    int M = in_sizes[0] / DIM;
    int N = in_sizes[1] / DIM;

    auto align256 = [](size_t x) { return (x + 255) & ~(size_t)255; };
    size_t sz_invt = align256((size_t)N * 4);
    size_t sz_bfA = align256((size_t)M * DIM * 2);
    size_t sz_bfB = align256((size_t)N * DIM * 2);
    size_t common = sz_invt + sz_bfA + sz_bfB;
    size_t sz_sbest8 = align256((size_t)M * (N / 8) * 4);
    size_t sz_sbest16 = align256((size_t)M * (N / 16) * 4);

    int gsh = 0;  // 0 = fallback
    if ((M % 128) == 0 && (N % 2048) == 0 && N / 8 <= 1024 &&
        ws_size >= common + sz_sbest8)
        gsh = 3;
    else if ((M % 128) == 0 && (N % 4096) == 0 && N / 16 <= 1024 &&
             ws_size >= common + sz_sbest16)
        gsh = 4;

    if (gsh) {
        char* p = (char*)d_ws;
        float* inv_t = (float*)p;                 p += sz_invt;
        unsigned short* bfA = (unsigned short*)p; p += sz_bfA;
        unsigned short* bfB = (unsigned short*)p; p += sz_bfB;
        float* sbest = (float*)p;
        int ngroups = N >> gsh;

        int n8a = M * DIM / 8;
        convertA_kernel<<<dim3((n8a + 255) / 256), 256, 0, stream>>>(src, bfA, n8a);
        convertB_norm_kernel<<<dim3((N + 3) / 4), 256, 0, stream>>>(tgt, bfB, inv_t, N);
        if (gsh == 3)
            mfma_argmax_kernel<8><<<dim3(M / 128, N / 128), 256, 0, stream>>>(
                bfA, bfB, inv_t, sbest, M, N);
        else
            mfma_argmax_kernel<16><<<dim3(M / 128, N / 128), 256, 0, stream>>>(
                bfA, bfB, inv_t, sbest, M, N);
        flag_refine_kernel<<<dim3(M), 256, 0, stream>>>(
            sbest, src, tgt, inv_t, out, ngroups, gsh);
    } else {
        char* ws = (char*)d_ws;
        float* sbest = (float*)ws;
        int* sidx = (int*)(ws + (size_t)NSTRIPES * M * sizeof(float));
        float* inv_t = (float*)(ws + (size_t)NSTRIPES * M * (sizeof(float) + sizeof(int)));
        inv_norm_kernel<<<dim3((N + 3) / 4), 256, 0, stream>>>(tgt, inv_t, N);
        fused_argmax_kernel<<<dim3(M / 128, NSTRIPES), 256, 0, stream>>>(
            src, tgt, inv_t, sbest, sidx, M, N);
        gather_kernel<<<dim3(M), 256, 0, stream>>>(tgt, sbest, sidx, out, M);
    }
}